// Round 5
// baseline (129.907 us; speedup 1.0000x reference)
//
#include <hip/hip_runtime.h>
#include <hip/hip_bf16.h>
#include <cstdint>
#include <cstddef>

// ---------- types ----------
typedef __bf16 bf16x8 __attribute__((ext_vector_type(8)));
typedef float  f32x4  __attribute__((ext_vector_type(4)));

static constexpr int B  = 16;
static constexpr int T  = 4096;
static constexpr int D  = 256;
static constexpr int M  = B * T;          // 65536 rows
static constexpr int SEGS = 64;           // segments along T
static constexpr int SEGL = T / SEGS;     // 64 steps per segment

// ---------- build fragment-major interleaved bf16 weights ----------
// Wp_s element layout: [(ks*32 + fg)*64 + lane] * 8 bf16 elems, where
//   fg = vcol>>4 (0..31), lane = kg*16 + rl, elem ko in [0,8)
//   stored value = W_{s,gate}[rc][ks*32 + kg*8 + ko]
// vcol decomposition: w = fg>>2 (col-wave 0..7), f = fg&3, q = f>>1,
//   gate = f&1, rc = w*32 + 2*rl + q  (lane rl holds 2 ADJACENT real cols)
__global__ void cvt_w(const float* __restrict__ W0, const float* __restrict__ W1,
                      const float* __restrict__ W2, const float* __restrict__ W3,
                      __bf16* __restrict__ wp) {
    int i = blockIdx.x * blockDim.x + threadIdx.x;   // 0..32767
    int s    = i >> 14;
    int r    = i & 16383;
    int ks   = r >> 11;          // 0..7
    int fg   = (r >> 6) & 31;    // 0..31
    int lane = r & 63;
    int kg = lane >> 4, rl = lane & 15;
    int w = fg >> 2, f = fg & 3;
    int q = f >> 1, gate = f & 1;
    int rc = w * 32 + 2 * rl + q;
    const float* src = (s == 0) ? (gate ? W1 : W0) : (gate ? W3 : W2);
    const float* p = src + (size_t)rc * 256 + ks * 32 + kg * 8;
    bf16x8 o;
#pragma unroll
    for (int j = 0; j < 8; ++j) o[j] = (__bf16)p[j];
    *reinterpret_cast<bf16x8*>(wp + (size_t)s * 131072 +
                               ((size_t)((ks * 32 + fg) * 64 + lane)) * 8) = o;
}

// ---------- fused two-stage gated-linear kernel (occupancy-first config) ----
// Block: 32 rows x 512 virtual cols (256 real), 1024 threads / 16 waves.
// Wave (rw, cw): rw = wid>>3 owns rows rw*16..+16, cw = wid&7 owns real cols
// [cw*32, cw*32+32) via 4 gate-interleaved fragments. acc = 4 f32x4 = 16 regs;
// target <=64 VGPR/wave -> 8 waves/SIMD -> 32 waves/CU (2x r3's TLP).
// LDS: ONE 16 KiB tile (x staged bf16, then h written IN PLACE after a
// barrier; x is dead once stage-0 ends). No ftile: scan_seg is standalone.
__launch_bounds__(1024, 8)
__global__ void gln_fused(const float* __restrict__ x,
                          const __bf16* __restrict__ wp,
                          const float* __restrict__ b0, const float* __restrict__ b1,
                          const float* __restrict__ b2, const float* __restrict__ b3,
                          float* __restrict__ out) {
    __shared__ char tile[16384];           // [32][256] bf16, 16B-chunk XOR swizzle

    const int tid  = threadIdx.x;          // 0..1023
    const int lane = tid & 63;
    const int wid  = tid >> 6;             // 0..15
    const int rl   = lane & 15;
    const int kg   = lane >> 4;            // 0..3
    const int cw   = wid & 7;              // col-wave 0..7
    const int rw   = wid >> 3;             // row-half 0..1
    const int row0 = blockIdx.x * 32;

    // per-wave weight base pointers (stage 0 / stage 1); fg = cw*4 + f
    const __bf16* wv0 = wp + ((size_t)(cw * 4) * 64 + lane) * 8;
    const __bf16* wv1 = wv0 + 131072;

    // ---- stage x rows [row0, row0+32) into LDS as bf16 ----
    {
        int r  = tid >> 5;         // 0..31
        int c0 = tid & 31;         // 16B-chunk 0..31
        const float4* p = reinterpret_cast<const float4*>(
            x + (size_t)(row0 + r) * 256 + c0 * 8);
        float4 v0 = p[0], v1 = p[1];
        bf16x8 o = { (__bf16)v0.x, (__bf16)v0.y, (__bf16)v0.z, (__bf16)v0.w,
                     (__bf16)v1.x, (__bf16)v1.y, (__bf16)v1.z, (__bf16)v1.w };
        *reinterpret_cast<bf16x8*>(&tile[r * 512 + ((c0 ^ (r & 7)) * 16)]) = o;
    }
    __syncthreads();

    f32x4 acc[4];

    // one GEMM stage: A from LDS (wave's 16 rows, K=256), B streamed from L2
    auto run_stage = [&](const __bf16* wvb) {
#pragma unroll
        for (int f = 0; f < 4; ++f) acc[f] = (f32x4){0.f, 0.f, 0.f, 0.f};
        const int arow = (rw * 16 + rl) * 512;
#pragma unroll 2
        for (int ks = 0; ks < 8; ++ks) {
            bf16x8 bR[4];
#pragma unroll
            for (int f = 0; f < 4; ++f)
                bR[f] = *reinterpret_cast<const bf16x8*>(wvb + ks * 16384 + f * 512);
            int ck = (ks * 4 + kg) ^ (rl & 7);
            bf16x8 aR = *reinterpret_cast<const bf16x8*>(&tile[arow + ck * 16]);
#pragma unroll
            for (int f = 0; f < 4; ++f)
                acc[f] = __builtin_amdgcn_mfma_f32_16x16x32_bf16(aR, bR[f], acc[f],
                                                                 0, 0, 0);
        }
    };

    const int rc0 = cw * 32 + 2 * rl;      // even real col of this lane

    // ---- stage 0: h = (x@W0^T+b0) * sigmoid(x@W1^T+b1) ----
    run_stage(wv0);
    __syncthreads();                       // all x reads done before h overwrite
    {
        float2 bb0 = *reinterpret_cast<const float2*>(b0 + rc0);
        float2 bb1 = *reinterpret_cast<const float2*>(b1 + rc0);
        int cb  = rc0 * 2;                 // byte col (even -> 4-aligned)
        int ck  = cb >> 4;
        int off = cb & 15;
#pragma unroll
        for (int j = 0; j < 4; ++j) {
            int row = rw * 16 + kg * 4 + j;
            float he = (acc[0][j] + bb0.x) *
                       (1.0f / (1.0f + __expf(-(acc[1][j] + bb1.x))));
            float ho = (acc[2][j] + bb0.y) *
                       (1.0f / (1.0f + __expf(-(acc[3][j] + bb1.y))));
            unsigned short ue = __builtin_bit_cast(unsigned short, (__bf16)he);
            unsigned short uo = __builtin_bit_cast(unsigned short, (__bf16)ho);
            unsigned int u = ((unsigned int)uo << 16) | (unsigned int)ue;
            *reinterpret_cast<unsigned int*>(
                &tile[row * 512 + ((ck ^ (row & 7)) * 16) + off]) = u;
        }
    }
    __syncthreads();

    // ---- stage 1: out = (h@W2^T+b2) * sigmoid(h@W3^T+b3), to global f32 ----
    run_stage(wv1);
    {
        float2 bb2 = *reinterpret_cast<const float2*>(b2 + rc0);
        float2 bb3 = *reinterpret_cast<const float2*>(b3 + rc0);
#pragma unroll
        for (int j = 0; j < 4; ++j) {
            int row = rw * 16 + kg * 4 + j;
            float he = (acc[0][j] + bb2.x) *
                       (1.0f / (1.0f + __expf(-(acc[1][j] + bb3.x))));
            float ho = (acc[2][j] + bb2.y) *
                       (1.0f / (1.0f + __expf(-(acc[3][j] + bb3.y))));
            float2 o; o.x = he; o.y = ho;
            *reinterpret_cast<float2*>(out + (size_t)(row0 + row) * 256 + rc0) = o;
        }
    }
    // no trailing barrier: stores drain while the next block launches
}

// ---------- scan phase 1: per-segment max-plus composition ----------
__global__ void scan_seg(const float* __restrict__ bmat, float2* __restrict__ seg_am) {
    int tid   = blockIdx.x * blockDim.x + threadIdx.x;
    int c     = tid & 255;
    int rest  = tid >> 8;
    int batch = rest & 15;
    int seg   = rest >> 4;
    const float* base = bmat + (size_t)batch * T * D;
    float A = 0.f, Mx = -1e30f;
    int t0 = seg * SEGL;
#pragma unroll 8
    for (int i = 0; i < SEGL; ++i) {
        int t = t0 + i;
        float v = base[(size_t)t * 256 + ((c + t) & 255)];
        A += v;
        Mx = fmaxf(Mx + v, 0.f);
    }
    float2 o; o.x = A; o.y = Mx;
    seg_am[(size_t)(batch * SEGS + seg) * 256 + c] = o;
}

// ---------- scan phase 2: sequential scan over segment boundaries ----------
__global__ void scan_bound(const float2* __restrict__ seg_am,
                           const float* __restrict__ hidden,
                           float* __restrict__ seg_state) {
    int tid   = blockIdx.x * blockDim.x + threadIdx.x;
    int c     = tid & 255;
    int batch = tid >> 8;
    float s = hidden[batch * 256 + ((c + 255) & 255)];
    for (int seg = 0; seg < SEGS; ++seg) {
        seg_state[(size_t)(batch * SEGS + seg) * 256 + c] = s;
        float2 am = seg_am[(size_t)(batch * SEGS + seg) * 256 + c];
        s = fmaxf(s + am.x, am.y);
    }
}

// ---------- scan phase 3: replay segment, write outputs in-place ----------
__global__ void scan_apply(float* __restrict__ bio,
                           const float* __restrict__ seg_state,
                           float* __restrict__ last) {
    int tid   = blockIdx.x * blockDim.x + threadIdx.x;
    int c     = tid & 255;
    int rest  = tid >> 8;
    int batch = rest & 15;
    int seg   = rest >> 4;
    float s = seg_state[(size_t)(batch * SEGS + seg) * 256 + c];
    float* base = bio + (size_t)batch * T * D;
    int t0 = seg * SEGL;
#pragma unroll 8
    for (int i = 0; i < SEGL; ++i) {
        int t = t0 + i;
        size_t idx = (size_t)t * 256 + ((c + t) & 255);
        float v = base[idx];
        s = fmaxf(s + v, 0.f);
        base[idx] = s;
    }
    if (seg == SEGS - 1) last[batch * 256 + ((c + 255) & 255)] = s;
}

// ---------- launch ----------
extern "C" void kernel_launch(void* const* d_in, const int* in_sizes, int n_in,
                              void* d_out, int out_size, void* d_ws, size_t ws_size,
                              hipStream_t stream) {
    const float* x      = (const float*)d_in[0];
    const float* hidden = (const float*)d_in[1];
    const float* W0 = (const float*)d_in[2];
    const float* b0 = (const float*)d_in[3];
    const float* W1 = (const float*)d_in[4];
    const float* b1 = (const float*)d_in[5];
    const float* W2 = (const float*)d_in[6];
    const float* b2 = (const float*)d_in[7];
    const float* W3 = (const float*)d_in[8];
    const float* b3 = (const float*)d_in[9];

    float* out  = (float*)d_out;
    float* last = out + (size_t)M * D;

    char* ws = (char*)d_ws;
    __bf16* wpb       = (__bf16*)ws;                     // 524,288 B (Wp0, Wp1)
    float2* seg_am    = (float2*)(ws + 524288);          // 2,097,152 B
    float*  seg_state = (float*)(ws + 524288 + 2097152); // 1,048,576 B

    cvt_w<<<128, 256, 0, stream>>>(W0, W1, W2, W3, wpb);
    gln_fused<<<M / 32, 1024, 0, stream>>>(x, wpb, b0, b1, b2, b3, out);

    scan_seg<<<(B * D * SEGS) / 256, 256, 0, stream>>>(out, seg_am);
    scan_bound<<<B * D / 256, 256, 0, stream>>>(seg_am, hidden, seg_state);
    scan_apply<<<(B * D * SEGS) / 256, 256, 0, stream>>>(out, seg_state, last);
}

// Round 6
// 95.763 us; speedup vs baseline: 1.3565x; 1.3565x over previous
//
#include <hip/hip_runtime.h>
#include <hip/hip_bf16.h>
#include <cstdint>
#include <cstddef>

// ---------- types ----------
typedef __bf16 bf16x8 __attribute__((ext_vector_type(8)));
typedef float  f32x4  __attribute__((ext_vector_type(4)));

static constexpr int B  = 16;
static constexpr int T  = 4096;
static constexpr int D  = 256;
static constexpr int M  = B * T;          // 65536 rows
static constexpr int SEGS = 64;           // segments along T
static constexpr int SEGL = T / SEGS;     // 64 steps per segment

// ---------- build fragment-major interleaved bf16 weights ----------
// Wp_s element layout: [(ks*32 + fg)*64 + lane] * 8 bf16 elems, where
//   fg = vcol>>4 (0..31), lane = kg*16 + rl, elem ko in [0,8)
//   stored value = W_{s,gate}[rc][ks*32 + kg*8 + ko]
// vcol decomposition: w = fg>>2 (col-wave 0..7), f = fg&3, q = f>>1,
//   gate = f&1, rc = w*32 + 2*rl + q  (lane rl holds 2 ADJACENT real cols)
__global__ void cvt_w(const float* __restrict__ W0, const float* __restrict__ W1,
                      const float* __restrict__ W2, const float* __restrict__ W3,
                      __bf16* __restrict__ wp) {
    int i = blockIdx.x * blockDim.x + threadIdx.x;   // 0..32767
    int s    = i >> 14;
    int r    = i & 16383;
    int ks   = r >> 11;          // 0..7
    int fg   = (r >> 6) & 31;    // 0..31
    int lane = r & 63;
    int kg = lane >> 4, rl = lane & 15;
    int w = fg >> 2, f = fg & 3;
    int q = f >> 1, gate = f & 1;
    int rc = w * 32 + 2 * rl + q;
    const float* src = (s == 0) ? (gate ? W1 : W0) : (gate ? W3 : W2);
    const float* p = src + (size_t)rc * 256 + ks * 32 + kg * 8;
    bf16x8 o;
#pragma unroll
    for (int j = 0; j < 8; ++j) o[j] = (__bf16)p[j];
    *reinterpret_cast<bf16x8*>(wp + (size_t)s * 131072 +
                               ((size_t)((ks * 32 + fg) * 64 + lane)) * 8) = o;
}

// ---------- fused two-stage gated-linear kernel ----------
// Block: 64 rows x 512 virtual cols (256 real), 512 threads / 8 waves.
// Wave w owns real cols [w*32, w*32+32), 2 adjacent cols/lane.
// LDS: ONE 32 KiB tile (x staged bf16; h overwrites IN PLACE after stage 0)
// -> 4 blocks/CU at ~64 VGPR (32 waves/CU).
// Swizzle (conflict-free, verified bank math): 16B-chunk
//   physical = logical ^ ((row&7)<<2)
// A-reads: 64 lanes -> 32 distinct chunks x 2 lanes = free (was 8-way).
// B streamed from L2 as per-lane-contiguous fragments, 2-deep pipelined.
__launch_bounds__(512, 4)
__global__ void gln_fused(const float* __restrict__ x,
                          const __bf16* __restrict__ wp,
                          const float* __restrict__ b0, const float* __restrict__ b1,
                          const float* __restrict__ b2, const float* __restrict__ b3,
                          float* __restrict__ out) {
    __shared__ char tile[32768];           // [64][256] bf16, chunk-XOR swizzle

    const int tid  = threadIdx.x;          // 0..511
    const int lane = tid & 63;
    const int wid  = tid >> 6;             // 0..7
    const int rl   = lane & 15;
    const int kg   = lane >> 4;            // 0..3
    const int row0 = blockIdx.x * 64;

    // per-wave weight base pointers (stage 0 / stage 1); fg = wid*4 + f
    const __bf16* wv0 = wp + ((size_t)(wid * 4) * 64 + lane) * 8;
    const __bf16* wv1 = wv0 + 131072;

    bf16x8 bbuf[2][4];
    auto loadB = [&](int p, const __bf16* wvb, int ks) {
#pragma unroll
        for (int f = 0; f < 4; ++f)
            bbuf[p][f] = *reinterpret_cast<const bf16x8*>(wvb + ks * 16384 + f * 512);
    };

    // ---- stage x rows [row0, row0+64) into LDS as bf16 ----
    {
        int r  = tid >> 3;         // 0..63
        int c0 = tid & 7;          // base 16B-chunk
        const float* xr = x + (size_t)(row0 + r) * 256;
        float4 xa[4][2];
#pragma unroll
        for (int ci = 0; ci < 4; ++ci) {
            const float4* p = reinterpret_cast<const float4*>(xr + (c0 + ci * 8) * 8);
            xa[ci][0] = p[0];
            xa[ci][1] = p[1];
        }
#pragma unroll
        for (int ci = 0; ci < 4; ++ci) {
            int ck = c0 + ci * 8;  // logical chunk 0..31
            int pc = ck ^ ((r & 7) << 2);
            bf16x8 o = { (__bf16)xa[ci][0].x, (__bf16)xa[ci][0].y,
                         (__bf16)xa[ci][0].z, (__bf16)xa[ci][0].w,
                         (__bf16)xa[ci][1].x, (__bf16)xa[ci][1].y,
                         (__bf16)xa[ci][1].z, (__bf16)xa[ci][1].w };
            *reinterpret_cast<bf16x8*>(&tile[r * 512 + pc * 16]) = o;
        }
    }
    loadB(0, wv0, 0);              // stage-0 ks0 prefetch, hidden under staging
    __syncthreads();

    f32x4 acc[4][4];

    // one GEMM stage: A from LDS (64 rows, K=256), B 2-deep pipelined from L2.
    // Assumes bbuf[0] holds this stage's ks=0 fragments on entry.
    auto run_stage = [&](const __bf16* wvb) {
#pragma unroll
        for (int m = 0; m < 4; ++m)
#pragma unroll
            for (int f = 0; f < 4; ++f) acc[m][f] = (f32x4){0.f, 0.f, 0.f, 0.f};
#pragma unroll
        for (int ks = 0; ks < 8; ++ks) {
            if (ks < 7) loadB((ks + 1) & 1, wvb, ks + 1);   // prefetch next ks
            bf16x8 aR[4];
#pragma unroll
            for (int m = 0; m < 4; ++m) {
                int row = m * 16 + rl;
                int pc  = (ks * 4 + kg) ^ ((row & 7) << 2);  // row&7 == rl&7
                aR[m] = *reinterpret_cast<const bf16x8*>(&tile[row * 512 + pc * 16]);
            }
#pragma unroll
            for (int m = 0; m < 4; ++m)
#pragma unroll
                for (int f = 0; f < 4; ++f)
                    acc[m][f] = __builtin_amdgcn_mfma_f32_16x16x32_bf16(
                        aR[m], bbuf[ks & 1][f], acc[m][f], 0, 0, 0);
        }
    };

    const int rc0 = wid * 32 + 2 * rl;     // even real col of this lane

    // ---- stage 0: h = (x@W0^T+b0) * sigmoid(x@W1^T+b1) ----
    run_stage(wv0);
    loadB(0, wv1, 0);              // stage-1 ks0 prefetch
    __syncthreads();               // all x reads done before in-place overwrite
    {
        float2 bb0 = *reinterpret_cast<const float2*>(b0 + rc0);
        float2 bb1 = *reinterpret_cast<const float2*>(b1 + rc0);
        int cb  = rc0 * 2;                 // byte col (4-aligned)
        int ck  = cb >> 4;                 // logical chunk
        int off = cb & 15;
#pragma unroll
        for (int m = 0; m < 4; ++m)
#pragma unroll
            for (int j = 0; j < 4; ++j) {
                int row = m * 16 + kg * 4 + j;
                float he = (acc[m][0][j] + bb0.x) *
                           (1.0f / (1.0f + __expf(-(acc[m][1][j] + bb1.x))));
                float ho = (acc[m][2][j] + bb0.y) *
                           (1.0f / (1.0f + __expf(-(acc[m][3][j] + bb1.y))));
                unsigned short ue = __builtin_bit_cast(unsigned short, (__bf16)he);
                unsigned short uo = __builtin_bit_cast(unsigned short, (__bf16)ho);
                unsigned int u = ((unsigned int)uo << 16) | (unsigned int)ue;
                int pc = ck ^ ((row & 7) << 2);
                *reinterpret_cast<unsigned int*>(&tile[row * 512 + pc * 16 + off]) = u;
            }
    }
    __syncthreads();

    // ---- stage 1: out = (h@W2^T+b2) * sigmoid(h@W3^T+b3), to global f32 ----
    run_stage(wv1);
    {
        float2 bb2 = *reinterpret_cast<const float2*>(b2 + rc0);
        float2 bb3 = *reinterpret_cast<const float2*>(b3 + rc0);
#pragma unroll
        for (int m = 0; m < 4; ++m)
#pragma unroll
            for (int j = 0; j < 4; ++j) {
                int row = m * 16 + kg * 4 + j;
                float he = (acc[m][0][j] + bb2.x) *
                           (1.0f / (1.0f + __expf(-(acc[m][1][j] + bb3.x))));
                float ho = (acc[m][2][j] + bb2.y) *
                           (1.0f / (1.0f + __expf(-(acc[m][3][j] + bb3.y))));
                float2 o; o.x = he; o.y = ho;
                *reinterpret_cast<float2*>(out + (size_t)(row0 + row) * 256 + rc0) = o;
            }
    }
    // no trailing barrier: stores drain while other blocks compute
}

// ---------- scan phase 1: per-segment max-plus composition ----------
__global__ void scan_seg(const float* __restrict__ bmat, float2* __restrict__ seg_am) {
    int tid   = blockIdx.x * blockDim.x + threadIdx.x;
    int c     = tid & 255;
    int rest  = tid >> 8;
    int batch = rest & 15;
    int seg   = rest >> 4;
    const float* base = bmat + (size_t)batch * T * D;
    float A = 0.f, Mx = -1e30f;
    int t0 = seg * SEGL;
#pragma unroll 8
    for (int i = 0; i < SEGL; ++i) {
        int t = t0 + i;
        float v = base[(size_t)t * 256 + ((c + t) & 255)];
        A += v;
        Mx = fmaxf(Mx + v, 0.f);
    }
    float2 o; o.x = A; o.y = Mx;
    seg_am[(size_t)(batch * SEGS + seg) * 256 + c] = o;
}

// ---------- scan phase 2: sequential scan over segment boundaries ----------
__global__ void scan_bound(const float2* __restrict__ seg_am,
                           const float* __restrict__ hidden,
                           float* __restrict__ seg_state) {
    int tid   = blockIdx.x * blockDim.x + threadIdx.x;
    int c     = tid & 255;
    int batch = tid >> 8;
    float s = hidden[batch * 256 + ((c + 255) & 255)];
    for (int seg = 0; seg < SEGS; ++seg) {
        seg_state[(size_t)(batch * SEGS + seg) * 256 + c] = s;
        float2 am = seg_am[(size_t)(batch * SEGS + seg) * 256 + c];
        s = fmaxf(s + am.x, am.y);
    }
}

// ---------- scan phase 3: replay segment, write outputs in-place ----------
__global__ void scan_apply(float* __restrict__ bio,
                           const float* __restrict__ seg_state,
                           float* __restrict__ last) {
    int tid   = blockIdx.x * blockDim.x + threadIdx.x;
    int c     = tid & 255;
    int rest  = tid >> 8;
    int batch = rest & 15;
    int seg   = rest >> 4;
    float s = seg_state[(size_t)(batch * SEGS + seg) * 256 + c];
    float* base = bio + (size_t)batch * T * D;
    int t0 = seg * SEGL;
#pragma unroll 8
    for (int i = 0; i < SEGL; ++i) {
        int t = t0 + i;
        size_t idx = (size_t)t * 256 + ((c + t) & 255);
        float v = base[idx];
        s = fmaxf(s + v, 0.f);
        base[idx] = s;
    }
    if (seg == SEGS - 1) last[batch * 256 + ((c + 255) & 255)] = s;
}

// ---------- launch ----------
extern "C" void kernel_launch(void* const* d_in, const int* in_sizes, int n_in,
                              void* d_out, int out_size, void* d_ws, size_t ws_size,
                              hipStream_t stream) {
    const float* x      = (const float*)d_in[0];
    const float* hidden = (const float*)d_in[1];
    const float* W0 = (const float*)d_in[2];
    const float* b0 = (const float*)d_in[3];
    const float* W1 = (const float*)d_in[4];
    const float* b1 = (const float*)d_in[5];
    const float* W2 = (const float*)d_in[6];
    const float* b2 = (const float*)d_in[7];
    const float* W3 = (const float*)d_in[8];
    const float* b3 = (const float*)d_in[9];

    float* out  = (float*)d_out;
    float* last = out + (size_t)M * D;

    char* ws = (char*)d_ws;
    __bf16* wpb       = (__bf16*)ws;                     // 524,288 B (Wp0, Wp1)
    float2* seg_am    = (float2*)(ws + 524288);          // 2,097,152 B
    float*  seg_state = (float*)(ws + 524288 + 2097152); // 1,048,576 B

    cvt_w<<<128, 256, 0, stream>>>(W0, W1, W2, W3, wpb);
    gln_fused<<<M / 64, 512, 0, stream>>>(x, wpb, b0, b1, b2, b3, out);

    scan_seg<<<(B * D * SEGS) / 256, 256, 0, stream>>>(out, seg_am);
    scan_bound<<<B * D / 256, 256, 0, stream>>>(seg_am, hidden, seg_state);
    scan_apply<<<(B * D * SEGS) / 256, 256, 0, stream>>>(out, seg_state, last);
}

// Round 7
// 88.106 us; speedup vs baseline: 1.4744x; 1.0869x over previous
//
#include <hip/hip_runtime.h>
#include <hip/hip_bf16.h>
#include <cstdint>
#include <cstddef>

// ---------- types ----------
typedef __bf16 bf16x8 __attribute__((ext_vector_type(8)));
typedef float  f32x4  __attribute__((ext_vector_type(4)));

static constexpr int B  = 16;
static constexpr int T  = 4096;
static constexpr int D  = 256;
static constexpr int M  = B * T;          // 65536 rows
static constexpr int SEGS = 64;           // segments along T
static constexpr int SEGL = T / SEGS;     // 64 steps per segment

// ---------- build fragment-major interleaved bf16 weights ----------
// Wp_s element layout: [(ks*32 + fg)*64 + lane] * 8 bf16 elems, where
//   fg = vcol>>4 (0..31), lane = kg*16 + rl, elem ko in [0,8)
//   stored value = W_{s,gate}[rc][ks*32 + kg*8 + ko]
// vcol decomposition: w = fg>>2 (col-wave 0..7), f = fg&3, q = f>>1,
//   gate = f&1, rc = w*32 + 2*rl + q  (lane rl holds 2 ADJACENT real cols)
__global__ void cvt_w(const float* __restrict__ W0, const float* __restrict__ W1,
                      const float* __restrict__ W2, const float* __restrict__ W3,
                      __bf16* __restrict__ wp) {
    int i = blockIdx.x * blockDim.x + threadIdx.x;   // 0..32767
    int s    = i >> 14;
    int r    = i & 16383;
    int ks   = r >> 11;          // 0..7
    int fg   = (r >> 6) & 31;    // 0..31
    int lane = r & 63;
    int kg = lane >> 4, rl = lane & 15;
    int w = fg >> 2, f = fg & 3;
    int q = f >> 1, gate = f & 1;
    int rc = w * 32 + 2 * rl + q;
    const float* src = (s == 0) ? (gate ? W1 : W0) : (gate ? W3 : W2);
    const float* p = src + (size_t)rc * 256 + ks * 32 + kg * 8;
    bf16x8 o;
#pragma unroll
    for (int j = 0; j < 8; ++j) o[j] = (__bf16)p[j];
    *reinterpret_cast<bf16x8*>(wp + (size_t)s * 131072 +
                               ((size_t)((ks * 32 + fg) * 64 + lane)) * 8) = o;
}

// ---------- fused two-stage gated-linear + per-segment scan compose ----------
// Block: 64 rows x 512 virtual cols (256 real) = one (batch, segment).
// 512 threads / 8 waves; wave w owns real cols [w*32,+32), 2 adjacent/lane.
// LDS: ONE 32 KiB tile. Lifetimes: x (bf16, staged) -> h (bf16, in-place)
// -> ftile (f32 [32][256], row-split: rows 0-31 then rows 32-63), from which
// tid<256 compose the segment's max-plus (A,Mx) carrying state in regs.
// B streamed from L2 as per-lane-contiguous fragments, 2-deep pipelined.
// NOTE: SQ_LDS_BANK_CONFLICT ~= 4 x (wave ds_read_b128 count) is the b128
// intrinsic cost (m134: ~12cyc vs 8 ideal), NOT a fixable pattern conflict.
__launch_bounds__(512, 4)
__global__ void gln_fused(const float* __restrict__ x,
                          const __bf16* __restrict__ wp,
                          const float* __restrict__ b0, const float* __restrict__ b1,
                          const float* __restrict__ b2, const float* __restrict__ b3,
                          float* __restrict__ out,
                          float2* __restrict__ seg_am) {
    __shared__ char tile[32768];           // [64][256] bf16, chunk-XOR swizzle

    const int tid  = threadIdx.x;          // 0..511
    const int lane = tid & 63;
    const int wid  = tid >> 6;             // 0..7
    const int rl   = lane & 15;
    const int kg   = lane >> 4;            // 0..3
    const int row0 = blockIdx.x * 64;

    // per-wave weight base pointers (stage 0 / stage 1); fg = wid*4 + f
    const __bf16* wv0 = wp + ((size_t)(wid * 4) * 64 + lane) * 8;
    const __bf16* wv1 = wv0 + 131072;

    bf16x8 bbuf[2][4];
    auto loadB = [&](int p, const __bf16* wvb, int ks) {
#pragma unroll
        for (int f = 0; f < 4; ++f)
            bbuf[p][f] = *reinterpret_cast<const bf16x8*>(wvb + ks * 16384 + f * 512);
    };

    // ---- stage x rows [row0, row0+64) into LDS as bf16 ----
    {
        int r  = tid >> 3;         // 0..63
        int c0 = tid & 7;          // base 16B-chunk
        const float* xr = x + (size_t)(row0 + r) * 256;
        float4 xa[4][2];
#pragma unroll
        for (int ci = 0; ci < 4; ++ci) {
            const float4* p = reinterpret_cast<const float4*>(xr + (c0 + ci * 8) * 8);
            xa[ci][0] = p[0];
            xa[ci][1] = p[1];
        }
#pragma unroll
        for (int ci = 0; ci < 4; ++ci) {
            int ck = c0 + ci * 8;  // logical chunk 0..31
            int pc = ck ^ ((r & 7) << 2);
            bf16x8 o = { (__bf16)xa[ci][0].x, (__bf16)xa[ci][0].y,
                         (__bf16)xa[ci][0].z, (__bf16)xa[ci][0].w,
                         (__bf16)xa[ci][1].x, (__bf16)xa[ci][1].y,
                         (__bf16)xa[ci][1].z, (__bf16)xa[ci][1].w };
            *reinterpret_cast<bf16x8*>(&tile[r * 512 + pc * 16]) = o;
        }
    }
    loadB(0, wv0, 0);              // stage-0 ks0 prefetch, hidden under staging
    __syncthreads();

    f32x4 acc[4][4];

    // one GEMM stage: A from LDS (64 rows, K=256), B 2-deep pipelined from L2.
    auto run_stage = [&](const __bf16* wvb) {
#pragma unroll
        for (int m = 0; m < 4; ++m)
#pragma unroll
            for (int f = 0; f < 4; ++f) acc[m][f] = (f32x4){0.f, 0.f, 0.f, 0.f};
#pragma unroll
        for (int ks = 0; ks < 8; ++ks) {
            if (ks < 7) loadB((ks + 1) & 1, wvb, ks + 1);   // prefetch next ks
            bf16x8 aR[4];
#pragma unroll
            for (int m = 0; m < 4; ++m) {
                int row = m * 16 + rl;
                int pc  = (ks * 4 + kg) ^ ((row & 7) << 2);
                aR[m] = *reinterpret_cast<const bf16x8*>(&tile[row * 512 + pc * 16]);
            }
#pragma unroll
            for (int m = 0; m < 4; ++m)
#pragma unroll
                for (int f = 0; f < 4; ++f)
                    acc[m][f] = __builtin_amdgcn_mfma_f32_16x16x32_bf16(
                        aR[m], bbuf[ks & 1][f], acc[m][f], 0, 0, 0);
        }
    };

    const int rc0 = wid * 32 + 2 * rl;     // even real col of this lane

    // ---- stage 0: h = (x@W0^T+b0) * sigmoid(x@W1^T+b1) ----
    run_stage(wv0);
    loadB(0, wv1, 0);              // stage-1 ks0 prefetch
    __syncthreads();               // all x reads done before in-place overwrite
    {
        float2 bb0 = *reinterpret_cast<const float2*>(b0 + rc0);
        float2 bb1 = *reinterpret_cast<const float2*>(b1 + rc0);
        int cb  = rc0 * 2;                 // byte col (4-aligned)
        int ck  = cb >> 4;                 // logical chunk
        int off = cb & 15;
#pragma unroll
        for (int m = 0; m < 4; ++m)
#pragma unroll
            for (int j = 0; j < 4; ++j) {
                int row = m * 16 + kg * 4 + j;
                float he = (acc[m][0][j] + bb0.x) *
                           (1.0f / (1.0f + __expf(-(acc[m][1][j] + bb1.x))));
                float ho = (acc[m][2][j] + bb0.y) *
                           (1.0f / (1.0f + __expf(-(acc[m][3][j] + bb1.y))));
                unsigned short ue = __builtin_bit_cast(unsigned short, (__bf16)he);
                unsigned short uo = __builtin_bit_cast(unsigned short, (__bf16)ho);
                unsigned int u = ((unsigned int)uo << 16) | (unsigned int)ue;
                int pc = ck ^ ((row & 7) << 2);
                *reinterpret_cast<unsigned int*>(&tile[row * 512 + pc * 16 + off]) = u;
            }
    }
    __syncthreads();

    // ---- stage 1: out = (h@W2^T+b2) * sigmoid(h@W3^T+b3) ----
    run_stage(wv1);

    // epilogue: gated values -> regs only (no LDS/global yet)
    float2 ov[16];
    {
        float2 bb2 = *reinterpret_cast<const float2*>(b2 + rc0);
        float2 bb3 = *reinterpret_cast<const float2*>(b3 + rc0);
#pragma unroll
        for (int m = 0; m < 4; ++m)
#pragma unroll
            for (int j = 0; j < 4; ++j) {
                int row = m * 16 + kg * 4 + j;
                float he = (acc[m][0][j] + bb2.x) *
                           (1.0f / (1.0f + __expf(-(acc[m][1][j] + bb3.x))));
                float ho = (acc[m][2][j] + bb2.y) *
                           (1.0f / (1.0f + __expf(-(acc[m][3][j] + bb3.y))));
                float2 o; o.x = he; o.y = ho;
                ov[m * 4 + j] = o;
            }
    }
    __syncthreads();               // all stage-1 h reads done; tile reusable

    // ---- row-split ftile + fused scan_seg compose (state in regs) ----
    float* ftile = reinterpret_cast<float*>(tile);   // [32][256] f32 = 32 KiB
    // write rows 0..31 (m = 0,1), f32, col XOR-swizzled (2-way banks = free)
#pragma unroll
    for (int m = 0; m < 2; ++m)
#pragma unroll
        for (int j = 0; j < 4; ++j) {
            int row = m * 16 + kg * 4 + j;
            int col = rc0 ^ ((row & 7) << 2);
            *reinterpret_cast<float2*>(&ftile[row * 256 + col]) = ov[m * 4 + j];
        }
    __syncthreads();

    const int batch = row0 >> 12;          // row0 / T
    const int t0    = row0 & 4095;
    const int seg   = t0 >> 6;
    float A = 0.f, Mx = -1e30f;
    int cc = 0;
    if (tid < 256) {
        cc = (tid + t0) & 255;
#pragma unroll 8
        for (int i = 0; i < 32; ++i) {
            int col = ((cc + i) & 255) ^ ((i & 7) << 2);
            float v = ftile[i * 256 + col];
            A += v;
            Mx = fmaxf(Mx + v, 0.f);
        }
    }
    __syncthreads();               // part-1 reads done before overwrite
    // write rows 32..63 (m = 2,3) into the same 32 physical rows
#pragma unroll
    for (int m = 2; m < 4; ++m)
#pragma unroll
        for (int j = 0; j < 4; ++j) {
            int row = m * 16 + kg * 4 + j;
            int pr  = row & 31;
            int col = rc0 ^ ((pr & 7) << 2);
            *reinterpret_cast<float2*>(&ftile[pr * 256 + col]) = ov[m * 4 + j];
        }
    __syncthreads();

    // global stores now; drain overlaps tail + other blocks (no barrier after)
#pragma unroll
    for (int m = 0; m < 4; ++m)
#pragma unroll
        for (int j = 0; j < 4; ++j) {
            int row = m * 16 + kg * 4 + j;
            *reinterpret_cast<float2*>(out + (size_t)(row0 + row) * 256 + rc0) =
                ov[m * 4 + j];
        }

    if (tid < 256) {
#pragma unroll 8
        for (int i = 32; i < 64; ++i) {
            int pr  = i - 32;
            int col = ((cc + i) & 255) ^ ((pr & 7) << 2);
            float v = ftile[pr * 256 + col];
            A += v;
            Mx = fmaxf(Mx + v, 0.f);
        }
        float2 o; o.x = A; o.y = Mx;
        seg_am[(size_t)(batch * SEGS + seg) * 256 + tid] = o;
    }
}

// ---------- scan apply with integrated boundary lookback ----------
// Block = one (batch, seg) x 256 cols. Redundantly composes seg_am[0..seg)
// (<=63 serial fmax steps, L2/L3-resident) instead of a separate scan_bound
// dispatch + seg_state round-trip.
__global__ void scan_apply(float* __restrict__ bio,
                           const float2* __restrict__ seg_am,
                           const float* __restrict__ hidden,
                           float* __restrict__ last) {
    int tid   = blockIdx.x * blockDim.x + threadIdx.x;
    int c     = tid & 255;
    int rest  = tid >> 8;
    int batch = rest & 15;
    int seg   = rest >> 4;
    float s = hidden[batch * 256 + ((c + 255) & 255)];
    const float2* am = seg_am + ((size_t)batch * SEGS) * 256 + c;
    for (int k = 0; k < seg; ++k) {
        float2 a = am[(size_t)k * 256];
        s = fmaxf(s + a.x, a.y);
    }
    float* base = bio + (size_t)batch * T * D;
    int t0 = seg * SEGL;
#pragma unroll 8
    for (int i = 0; i < SEGL; ++i) {
        int t = t0 + i;
        size_t idx = (size_t)t * 256 + ((c + t) & 255);
        float v = base[idx];
        s = fmaxf(s + v, 0.f);
        base[idx] = s;
    }
    if (seg == SEGS - 1) last[batch * 256 + ((c + 255) & 255)] = s;
}

// ---------- launch ----------
extern "C" void kernel_launch(void* const* d_in, const int* in_sizes, int n_in,
                              void* d_out, int out_size, void* d_ws, size_t ws_size,
                              hipStream_t stream) {
    const float* x      = (const float*)d_in[0];
    const float* hidden = (const float*)d_in[1];
    const float* W0 = (const float*)d_in[2];
    const float* b0 = (const float*)d_in[3];
    const float* W1 = (const float*)d_in[4];
    const float* b1 = (const float*)d_in[5];
    const float* W2 = (const float*)d_in[6];
    const float* b2 = (const float*)d_in[7];
    const float* W3 = (const float*)d_in[8];
    const float* b3 = (const float*)d_in[9];

    float* out  = (float*)d_out;
    float* last = out + (size_t)M * D;

    char* ws = (char*)d_ws;
    __bf16* wpb    = (__bf16*)ws;                 // 524,288 B (Wp0, Wp1)
    float2* seg_am = (float2*)(ws + 524288);      // 2,097,152 B

    cvt_w<<<128, 256, 0, stream>>>(W0, W1, W2, W3, wpb);
    gln_fused<<<M / 64, 512, 0, stream>>>(x, wpb, b0, b1, b2, b3, out, seg_am);
    scan_apply<<<(B * D * SEGS) / 256, 256, 0, stream>>>(out, seg_am, hidden, last);
}

// Round 8
// 84.300 us; speedup vs baseline: 1.5410x; 1.0451x over previous
//
#include <hip/hip_runtime.h>
#include <hip/hip_bf16.h>
#include <cstdint>
#include <cstddef>

// ---------- types ----------
typedef __bf16 bf16x8 __attribute__((ext_vector_type(8)));
typedef float  f32x4  __attribute__((ext_vector_type(4)));

static constexpr int B  = 16;
static constexpr int T  = 4096;
static constexpr int D  = 256;
static constexpr int M  = B * T;          // 65536 rows
static constexpr int SEGS = 64;           // segments along T
static constexpr int SEGL = T / SEGS;     // 64 steps per segment

// fast sigmoid: v_exp_f32 path + v_rcp_f32 (1-instr) instead of IEEE div
// (~10 instrs). Tolerance headroom: absmax already 0.0625 from bf16 GEMM;
// rcp approx error ~1 ulp.
__device__ __forceinline__ float sigmoid_fast(float v) {
    return __builtin_amdgcn_rcpf(1.0f + __expf(-v));
}

// ---------- build fragment-major interleaved bf16 weights ----------
// Wp_s element layout: [(ks*32 + fg)*64 + lane] * 8 bf16 elems, where
//   fg = vcol>>4 (0..31), lane = kg*16 + rl, elem ko in [0,8)
//   stored value = W_{s,gate}[rc][ks*32 + kg*8 + ko]
// vcol decomposition: w = fg>>2 (col-wave 0..7), f = fg&3, q = f>>1,
//   gate = f&1, rc = w*32 + 2*rl + q  (lane rl holds 2 ADJACENT real cols)
__global__ void cvt_w(const float* __restrict__ W0, const float* __restrict__ W1,
                      const float* __restrict__ W2, const float* __restrict__ W3,
                      __bf16* __restrict__ wp) {
    int i = blockIdx.x * blockDim.x + threadIdx.x;   // 0..32767
    int s    = i >> 14;
    int r    = i & 16383;
    int ks   = r >> 11;          // 0..7
    int fg   = (r >> 6) & 31;    // 0..31
    int lane = r & 63;
    int kg = lane >> 4, rl = lane & 15;
    int w = fg >> 2, f = fg & 3;
    int q = f >> 1, gate = f & 1;
    int rc = w * 32 + 2 * rl + q;
    const float* src = (s == 0) ? (gate ? W1 : W0) : (gate ? W3 : W2);
    const float* p = src + (size_t)rc * 256 + ks * 32 + kg * 8;
    bf16x8 o;
#pragma unroll
    for (int j = 0; j < 8; ++j) o[j] = (__bf16)p[j];
    *reinterpret_cast<bf16x8*>(wp + (size_t)s * 131072 +
                               ((size_t)((ks * 32 + fg) * 64 + lane)) * 8) = o;
}

// ---------- fused two-stage gated-linear + per-segment scan compose ----------
// Block: 64 rows x 512 virtual cols (256 real) = one (batch, segment).
// 512 threads / 8 waves; wave w owns real cols [w*32,+32), 2 adjacent/lane.
// LDS: ONE 32 KiB tile. Lifetimes: x (bf16, staged) -> h (bf16, in-place)
// -> ftile (f32 [32][256], row-split: rows 0-31 then rows 32-63), from which
// tid<256 compose the segment's max-plus (A,Mx) carrying state in regs.
// B streamed from L2 as per-lane-contiguous fragments, 2-deep pipelined.
// NOTE: SQ_LDS_BANK_CONFLICT ~= 4 x (wave ds_read_b128 count) is the b128
// intrinsic cost (m134: ~12cyc vs 8 ideal), NOT a fixable pattern conflict.
__launch_bounds__(512, 4)
__global__ void gln_fused(const float* __restrict__ x,
                          const __bf16* __restrict__ wp,
                          const float* __restrict__ b0, const float* __restrict__ b1,
                          const float* __restrict__ b2, const float* __restrict__ b3,
                          float* __restrict__ out,
                          float2* __restrict__ seg_am) {
    __shared__ char tile[32768];           // [64][256] bf16, chunk-XOR swizzle

    const int tid  = threadIdx.x;          // 0..511
    const int lane = tid & 63;
    const int wid  = tid >> 6;             // 0..7
    const int rl   = lane & 15;
    const int kg   = lane >> 4;            // 0..3
    const int row0 = blockIdx.x * 64;

    // per-wave weight base pointers (stage 0 / stage 1); fg = wid*4 + f
    const __bf16* wv0 = wp + ((size_t)(wid * 4) * 64 + lane) * 8;
    const __bf16* wv1 = wv0 + 131072;

    bf16x8 bbuf[2][4];
    auto loadB = [&](int p, const __bf16* wvb, int ks) {
#pragma unroll
        for (int f = 0; f < 4; ++f)
            bbuf[p][f] = *reinterpret_cast<const bf16x8*>(wvb + ks * 16384 + f * 512);
    };

    // ---- stage x rows [row0, row0+64) into LDS as bf16 ----
    {
        int r  = tid >> 3;         // 0..63
        int c0 = tid & 7;          // base 16B-chunk
        const float* xr = x + (size_t)(row0 + r) * 256;
        float4 xa[4][2];
#pragma unroll
        for (int ci = 0; ci < 4; ++ci) {
            const float4* p = reinterpret_cast<const float4*>(xr + (c0 + ci * 8) * 8);
            xa[ci][0] = p[0];
            xa[ci][1] = p[1];
        }
#pragma unroll
        for (int ci = 0; ci < 4; ++ci) {
            int ck = c0 + ci * 8;  // logical chunk 0..31
            int pc = ck ^ ((r & 7) << 2);
            bf16x8 o = { (__bf16)xa[ci][0].x, (__bf16)xa[ci][0].y,
                         (__bf16)xa[ci][0].z, (__bf16)xa[ci][0].w,
                         (__bf16)xa[ci][1].x, (__bf16)xa[ci][1].y,
                         (__bf16)xa[ci][1].z, (__bf16)xa[ci][1].w };
            *reinterpret_cast<bf16x8*>(&tile[r * 512 + pc * 16]) = o;
        }
    }
    loadB(0, wv0, 0);              // stage-0 ks0 prefetch, hidden under staging
    __syncthreads();

    f32x4 acc[4][4];

    // one GEMM stage: A from LDS (64 rows, K=256), B 2-deep pipelined from L2.
    auto run_stage = [&](const __bf16* wvb) {
#pragma unroll
        for (int m = 0; m < 4; ++m)
#pragma unroll
            for (int f = 0; f < 4; ++f) acc[m][f] = (f32x4){0.f, 0.f, 0.f, 0.f};
#pragma unroll
        for (int ks = 0; ks < 8; ++ks) {
            if (ks < 7) loadB((ks + 1) & 1, wvb, ks + 1);   // prefetch next ks
            bf16x8 aR[4];
#pragma unroll
            for (int m = 0; m < 4; ++m) {
                int row = m * 16 + rl;
                int pc  = (ks * 4 + kg) ^ ((row & 7) << 2);
                aR[m] = *reinterpret_cast<const bf16x8*>(&tile[row * 512 + pc * 16]);
            }
#pragma unroll
            for (int m = 0; m < 4; ++m)
#pragma unroll
                for (int f = 0; f < 4; ++f)
                    acc[m][f] = __builtin_amdgcn_mfma_f32_16x16x32_bf16(
                        aR[m], bbuf[ks & 1][f], acc[m][f], 0, 0, 0);
        }
    };

    const int rc0 = wid * 32 + 2 * rl;     // even real col of this lane

    // ---- stage 0: h = (x@W0^T+b0) * sigmoid(x@W1^T+b1) ----
    run_stage(wv0);
    loadB(0, wv1, 0);              // stage-1 ks0 prefetch
    __syncthreads();               // all x reads done before in-place overwrite
    {
        float2 bb0 = *reinterpret_cast<const float2*>(b0 + rc0);
        float2 bb1 = *reinterpret_cast<const float2*>(b1 + rc0);
        int cb  = rc0 * 2;                 // byte col (4-aligned)
        int ck  = cb >> 4;                 // logical chunk
        int off = cb & 15;
#pragma unroll
        for (int m = 0; m < 4; ++m)
#pragma unroll
            for (int j = 0; j < 4; ++j) {
                int row = m * 16 + kg * 4 + j;
                float he = (acc[m][0][j] + bb0.x) * sigmoid_fast(acc[m][1][j] + bb1.x);
                float ho = (acc[m][2][j] + bb0.y) * sigmoid_fast(acc[m][3][j] + bb1.y);
                unsigned short ue = __builtin_bit_cast(unsigned short, (__bf16)he);
                unsigned short uo = __builtin_bit_cast(unsigned short, (__bf16)ho);
                unsigned int u = ((unsigned int)uo << 16) | (unsigned int)ue;
                int pc = ck ^ ((row & 7) << 2);
                *reinterpret_cast<unsigned int*>(&tile[row * 512 + pc * 16 + off]) = u;
            }
    }
    __syncthreads();

    // ---- stage 1: out = (h@W2^T+b2) * sigmoid(h@W3^T+b3) ----
    run_stage(wv1);

    // epilogue: gated values -> regs only (no LDS/global yet)
    float2 ov[16];
    {
        float2 bb2 = *reinterpret_cast<const float2*>(b2 + rc0);
        float2 bb3 = *reinterpret_cast<const float2*>(b3 + rc0);
#pragma unroll
        for (int m = 0; m < 4; ++m)
#pragma unroll
            for (int j = 0; j < 4; ++j) {
                float he = (acc[m][0][j] + bb2.x) * sigmoid_fast(acc[m][1][j] + bb3.x);
                float ho = (acc[m][2][j] + bb2.y) * sigmoid_fast(acc[m][3][j] + bb3.y);
                float2 o; o.x = he; o.y = ho;
                ov[m * 4 + j] = o;
            }
    }
    __syncthreads();               // all stage-1 h reads done; tile reusable

    // ---- row-split ftile + fused scan_seg compose (state in regs) ----
    float* ftile = reinterpret_cast<float*>(tile);   // [32][256] f32 = 32 KiB
    // write rows 0..31 (m = 0,1), f32, col XOR-swizzled (2-way banks = free)
#pragma unroll
    for (int m = 0; m < 2; ++m)
#pragma unroll
        for (int j = 0; j < 4; ++j) {
            int row = m * 16 + kg * 4 + j;
            int col = rc0 ^ ((row & 7) << 2);
            *reinterpret_cast<float2*>(&ftile[row * 256 + col]) = ov[m * 4 + j];
        }
    __syncthreads();

    const int batch = row0 >> 12;          // row0 / T
    const int t0    = row0 & 4095;
    const int seg   = t0 >> 6;
    float A = 0.f, Mx = -1e30f;
    int cc = 0;
    if (tid < 256) {
        cc = (tid + t0) & 255;
#pragma unroll 8
        for (int i = 0; i < 32; ++i) {
            int col = ((cc + i) & 255) ^ ((i & 7) << 2);
            float v = ftile[i * 256 + col];
            A += v;
            Mx = fmaxf(Mx + v, 0.f);
        }
    }
    __syncthreads();               // part-1 reads done before overwrite
    // write rows 32..63 (m = 2,3) into the same 32 physical rows
#pragma unroll
    for (int m = 2; m < 4; ++m)
#pragma unroll
        for (int j = 0; j < 4; ++j) {
            int row = m * 16 + kg * 4 + j;
            int pr  = row & 31;
            int col = rc0 ^ ((pr & 7) << 2);
            *reinterpret_cast<float2*>(&ftile[pr * 256 + col]) = ov[m * 4 + j];
        }
    __syncthreads();

    // global stores now; drain overlaps tail + other blocks (no barrier after)
#pragma unroll
    for (int m = 0; m < 4; ++m)
#pragma unroll
        for (int j = 0; j < 4; ++j) {
            int row = m * 16 + kg * 4 + j;
            *reinterpret_cast<float2*>(out + (size_t)(row0 + row) * 256 + rc0) =
                ov[m * 4 + j];
        }

    if (tid < 256) {
#pragma unroll 8
        for (int i = 32; i < 64; ++i) {
            int pr  = i - 32;
            int col = ((cc + i) & 255) ^ ((pr & 7) << 2);
            float v = ftile[pr * 256 + col];
            A += v;
            Mx = fmaxf(Mx + v, 0.f);
        }
        float2 o; o.x = A; o.y = Mx;
        seg_am[(size_t)(batch * SEGS + seg) * 256 + tid] = o;
    }
}

// ---------- scan apply with integrated boundary lookback ----------
// Block = one (batch, seg) x 256 cols. Redundantly composes seg_am[0..seg)
// (<=63 serial fmax steps, L2/L3-resident) instead of a separate scan_bound
// dispatch + seg_state round-trip.
__global__ void scan_apply(float* __restrict__ bio,
                           const float2* __restrict__ seg_am,
                           const float* __restrict__ hidden,
                           float* __restrict__ last) {
    int tid   = blockIdx.x * blockDim.x + threadIdx.x;
    int c     = tid & 255;
    int rest  = tid >> 8;
    int batch = rest & 15;
    int seg   = rest >> 4;
    float s = hidden[batch * 256 + ((c + 255) & 255)];
    const float2* am = seg_am + ((size_t)batch * SEGS) * 256 + c;
    for (int k = 0; k < seg; ++k) {
        float2 a = am[(size_t)k * 256];
        s = fmaxf(s + a.x, a.y);
    }
    float* base = bio + (size_t)batch * T * D;
    int t0 = seg * SEGL;
#pragma unroll 8
    for (int i = 0; i < SEGL; ++i) {
        int t = t0 + i;
        size_t idx = (size_t)t * 256 + ((c + t) & 255);
        float v = base[idx];
        s = fmaxf(s + v, 0.f);
        base[idx] = s;
    }
    if (seg == SEGS - 1) last[batch * 256 + ((c + 255) & 255)] = s;
}

// ---------- launch ----------
extern "C" void kernel_launch(void* const* d_in, const int* in_sizes, int n_in,
                              void* d_out, int out_size, void* d_ws, size_t ws_size,
                              hipStream_t stream) {
    const float* x      = (const float*)d_in[0];
    const float* hidden = (const float*)d_in[1];
    const float* W0 = (const float*)d_in[2];
    const float* b0 = (const float*)d_in[3];
    const float* W1 = (const float*)d_in[4];
    const float* b1 = (const float*)d_in[5];
    const float* W2 = (const float*)d_in[6];
    const float* b2 = (const float*)d_in[7];
    const float* W3 = (const float*)d_in[8];
    const float* b3 = (const float*)d_in[9];

    float* out  = (float*)d_out;
    float* last = out + (size_t)M * D;

    char* ws = (char*)d_ws;
    __bf16* wpb    = (__bf16*)ws;                 // 524,288 B (Wp0, Wp1)
    float2* seg_am = (float2*)(ws + 524288);      // 2,097,152 B

    cvt_w<<<128, 256, 0, stream>>>(W0, W1, W2, W3, wpb);
    gln_fused<<<M / 64, 512, 0, stream>>>(x, wpb, b0, b1, b2, b3, out, seg_am);
    scan_apply<<<(B * D * SEGS) / 256, 256, 0, stream>>>(out, seg_am, hidden, last);
}